// Round 12
// baseline (507.534 us; speedup 1.0000x reference)
//
#include <hip/hip_runtime.h>
#include <stdint.h>

#define N_PTS 2048
#define NK 5
#define TOPK 512
#define NBUCK 128
#define NENT (N_PTS * NK)        // 10240
#define CAP_MAX 262144u

// frozen arithmetic (r9-verified bit-exact vs np oracle):
//   d2 = fma(dz,dz, fma(dx,dx, dy*dy)); d = sqrt(max(d2,0))
//   q = fdiv(diff*diff, 0.01f); temp = max(1-q,0); v = (L*temp)*A
// tie rule: value desc, flat idx asc (key (vb<<32)|~idx descending)

// ws layout (bytes):
//      0  src_ne_idx   int[10240]    (40960)
//  40960  src_ne_dist  f32[10240]    (40960)
//  81920  ref_ne_idx   int[10240]    (40960)
// 122880  ref_ne_dist  f32[10240]    (40960)
// 163840  rowmax       uint[2048]    (8192)
// 172032  counters     uint[8]       (32)   [0]=cand_count [3]=T
// 172064  bucket_cnt   uint[128]     (512)  (memset 0 per launch)
// 172576  bucket_cur   uint[128]     (512)
// 173088  bucket_off   uint[132]     (528)
// 173616  entries      uint64[10240] (81920)
// 255536  cand         uint64[cap]
#define OFF_SIDX   0
#define OFF_SDIST  40960
#define OFF_RIDX   81920
#define OFF_RDIST  122880
#define OFF_RMAX   163840
#define OFF_CNT    172032
#define OFF_BCNT   172064
#define OFF_BCUR   172576
#define OFF_BOFF   173088
#define OFF_ENT    173616
#define OFF_CAND   255536

__device__ __forceinline__ unsigned long long shflxor64(unsigned long long v, int mask) {
  unsigned lo = (unsigned)v, hi = (unsigned)(v >> 32);
  lo = (unsigned)__shfl_xor((int)lo, mask);
  hi = (unsigned)__shfl_xor((int)hi, mask);
  return ((unsigned long long)hi << 32) | lo;
}

// ---------------- KNN: 512 blocks, 8 points/block, 32 lanes/point ------------
__global__ __launch_bounds__(256) void knn_kernel(
    const float* __restrict__ src, const float* __restrict__ ref,
    int* __restrict__ sidx, float* __restrict__ sdist,
    int* __restrict__ ridx, float* __restrict__ rdist) {
  __shared__ float sx[N_PTS], sy[N_PTS], sz[N_PTS];
  const bool is_ref = blockIdx.x >= 256;
  const float* pts = is_ref ? ref : src;
  int*   oidx  = is_ref ? ridx : sidx;
  float* odist = is_ref ? rdist : sdist;
  const int blk = is_ref ? (blockIdx.x - 256) : blockIdx.x;

  for (int t = threadIdx.x; t < N_PTS; t += 256) {
    sx[t] = pts[3 * t + 0];
    sy[t] = pts[3 * t + 1];
    sz[t] = pts[3 * t + 2];
  }
  __syncthreads();

  const int p = blk * 8 + (threadIdx.x >> 5);
  const int u = threadIdx.x & 31;
  const float px = sx[p], py = sy[p], pz = sz[p];

  unsigned long long best[6];
#pragma unroll
  for (int k = 0; k < 6; ++k) best[k] = ~0ull;

  for (int j = u; j < N_PTS; j += 32) {
    float dx = __fsub_rn(px, sx[j]);
    float dy = __fsub_rn(py, sy[j]);
    float dz = __fsub_rn(pz, sz[j]);
    float d2 = __builtin_fmaf(dz, dz,
                 __builtin_fmaf(dx, dx, __fmul_rn(dy, dy)));
    float d = __fsqrt_rn(fmaxf(d2, 0.0f));
    unsigned long long key = (((unsigned long long)__float_as_uint(d)) << 32)
                           | (unsigned)j;
    if (key < best[5]) {
      best[5] = key;
#pragma unroll
      for (int k = 5; k >= 1; --k)
        if (best[k] < best[k - 1]) {
          unsigned long long t = best[k]; best[k] = best[k - 1]; best[k - 1] = t;
        }
    }
  }

  int h = 0;
  unsigned long long win[6];
#pragma unroll
  for (int round = 0; round < 6; ++round) {
    unsigned long long my = (h < 6) ? best[h] : ~0ull;
    unsigned long long m = my;
#pragma unroll
    for (int msk = 16; msk >= 1; msk >>= 1) {
      unsigned long long o = shflxor64(m, msk);
      if (o < m) m = o;
    }
    win[round] = m;
    if (my == m) ++h;
  }

  if (u == 0) {
#pragma unroll
    for (int m = 1; m <= NK; ++m) {     // drop win[0] == self (d = 0)
      oidx[p * NK + m - 1]  = (int)(win[m] & 0xFFFFFFFFull);
      odist[p * NK + m - 1] = __uint_as_float((unsigned)(win[m] >> 32));
    }
  }
}

__device__ __forceinline__ int bucket_of(float rd) {
  int b = (int)(rd * 64.0f);
  if (b < 0) b = 0;
  if (b > NBUCK - 1) b = NBUCK - 1;
  return b;
}

// ---------------- bucket build: count / prefix / scatter ---------------------
__global__ __launch_bounds__(1024) void bcount_kernel(
    const float* __restrict__ rdist, unsigned int* __restrict__ bcnt) {
  int t = blockIdx.x * 1024 + threadIdx.x;
  if (t < NENT) atomicAdd(&bcnt[bucket_of(rdist[t])], 1u);
}

__global__ __launch_bounds__(64) void bprefix_kernel(
    const unsigned int* __restrict__ bcnt, unsigned int* __restrict__ bcur,
    unsigned int* __restrict__ boff) {
  if (threadIdx.x == 0) {
    unsigned int acc = 0;
    for (int b = 0; b < NBUCK; ++b) {
      boff[b] = acc;
      bcur[b] = acc;
      acc += bcnt[b];
    }
    boff[NBUCK] = acc;
  }
}

// entry: (rd_bits << 32) | (r << 14) | (j << 11) | rn
__global__ __launch_bounds__(1024) void bscatter_kernel(
    const float* __restrict__ rdist, const int* __restrict__ ridx,
    unsigned int* __restrict__ bcur, unsigned long long* __restrict__ entries) {
  int t = blockIdx.x * 1024 + threadIdx.x;
  if (t < NENT) {
    float rd = rdist[t];
    int r = t / NK, j = t % NK;
    unsigned int rn = (unsigned int)ridx[t];
    unsigned int pos = atomicAdd(&bcur[bucket_of(rd)], 1u);
    entries[pos] = (((unsigned long long)__float_as_uint(rd)) << 32)
                 | ((unsigned int)r << 14) | ((unsigned int)j << 11) | rn;
  }
}

// Bucketed pa scan — NO LDS staging: Lsr and A2 gathered straight from L.
// Per i-iteration the A row base (sn_i) is wave-uniform -> the 8 KB row is
// L1-resident after first touch; same for this block's own L row.
// COLLECT=0: rowmax; COLLECT=1: collect candidates >= T.
template <int COLLECT>
__device__ __forceinline__ void pa_scan(
    const float* __restrict__ L,
    const int* __restrict__ sidx, const float* __restrict__ sdist,
    const unsigned int* __restrict__ boff,
    const unsigned long long* __restrict__ entries,
    int s, int tid,
    unsigned int* rowmax_out,                  // COLLECT=0
    unsigned int T, unsigned int* counters,    // COLLECT=1
    uint64_t* cand, unsigned int cap) {
  __shared__ float sdsh[NK];
  __shared__ int   snsh[NK];
  __shared__ unsigned int red[256];
  if (tid < NK) { snsh[tid] = sidx[s * NK + tid]; sdsh[tid] = sdist[s * NK + tid]; }
  __syncthreads();

  const float* __restrict__ Lrow = L + (size_t)s * N_PTS;

  unsigned int mymax = 0;
#pragma unroll
  for (int i = 0; i < NK; ++i) {
    const float sd_i = sdsh[i];
    const float* __restrict__ Arow = L + (size_t)snsh[i] * N_PTS;
    // conservative window: any temp>0 cell has |sd-rd| <= 0.1000001 < 0.1005
    float lo = __fsub_rn(sd_i, 0.1005f);
    float hi = __fadd_rn(sd_i, 0.1005f);
    int b0 = bucket_of(lo);
    int b1 = bucket_of(hi);
    unsigned int e0 = boff[b0], e1 = boff[b1 + 1];
    for (unsigned int e = e0 + tid; e < e1; e += 256) {
      unsigned long long ent = entries[e];
      float rdv = __uint_as_float((unsigned int)(ent >> 32));
      float diff = __fsub_rn(sd_i, rdv);
      float dsq  = __fmul_rn(diff, diff);
      if (dsq < 0.0101f) {
        float q    = __fdiv_rn(dsq, 0.01f);
        float temp = fmaxf(__fsub_rn(1.0f, q), 0.0f);
        if (temp > 0.0f) {
          unsigned int lo32 = (unsigned int)ent;
          unsigned int r  = (lo32 >> 14) & 0x7FFu;
          unsigned int rn = lo32 & 0x7FFu;
          float v = __fmul_rn(__fmul_rn(Lrow[r], temp), Arow[rn]);
          unsigned int vb = __float_as_uint(v);
          if (COLLECT == 0) {
            if (vb > mymax) mymax = vb;       // v>=0: bits monotone
          } else {
            if (v > 0.0f && vb >= T) {
              unsigned int j = (lo32 >> 11) & 7u;
              unsigned int pos = atomicAdd(&counters[0], 1u);
              if (pos < cap) {
                unsigned int idx = ((unsigned int)s * (unsigned int)N_PTS + r) * 25u
                                 + (unsigned int)i * 5u + j;
                cand[pos] = (((uint64_t)vb) << 32) | (uint64_t)((uint32_t)(~idx));
              }
            }
          }
        }
      }
    }
  }
  if (COLLECT == 0) {
    red[tid] = mymax;
    __syncthreads();
    for (int step = 128; step > 0; step >>= 1) {
      if (tid < step && red[tid + step] > red[tid]) red[tid] = red[tid + step];
      __syncthreads();
    }
    if (tid == 0) rowmax_out[s] = red[0];
  }
}

// ---------------- pass 1: per-row max (bucketed, atomic-free) ----------------
__global__ __launch_bounds__(256) void rowmax_kernel(
    const float* __restrict__ L,
    const int* __restrict__ sidx, const float* __restrict__ sdist,
    const unsigned int* __restrict__ boff,
    const unsigned long long* __restrict__ entries,
    unsigned int* __restrict__ rowmax) {
  pa_scan<0>(L, sidx, sdist, boff, entries, blockIdx.x, threadIdx.x,
             rowmax, 0, nullptr, nullptr, 0);
}

// ---------------- threshold: T = 512th-largest row max; zero counter ---------
__global__ __launch_bounds__(1024) void thresh_kernel(
    const unsigned int* __restrict__ rowmax, unsigned int* __restrict__ counters) {
  __shared__ unsigned int a[N_PTS];
  const int tid = threadIdx.x;
  for (int t = tid; t < N_PTS; t += 1024) a[t] = rowmax[t];
  __syncthreads();
  for (int k2 = 2; k2 <= N_PTS; k2 <<= 1) {
    for (int j2 = k2 >> 1; j2 > 0; j2 >>= 1) {
      for (int e = 0; e < N_PTS / 1024; ++e) {
        int i = tid + e * 1024;
        int pj = i ^ j2;
        if (pj > i) {
          bool blk = ((i & k2) == 0);
          unsigned int x = a[i], y = a[pj];
          if (blk ? (x < y) : (x > y)) { a[i] = y; a[pj] = x; }
        }
      }
      __syncthreads();
    }
  }
  if (tid == 0) {
    counters[3] = a[TOPK - 1];
    counters[0] = 0;
  }
}

// ---------------- pass 2: collect, skipping rows with rowmax < T -------------
__global__ __launch_bounds__(256) void collect_kernel(
    const float* __restrict__ L,
    const int* __restrict__ sidx, const float* __restrict__ sdist,
    const unsigned int* __restrict__ boff,
    const unsigned long long* __restrict__ entries,
    const unsigned int* __restrict__ rowmax,
    unsigned int* __restrict__ counters, uint64_t* __restrict__ cand,
    unsigned int cap) {
  const int s = blockIdx.x;
  const unsigned int T = counters[3];
  if (rowmax[s] < T) return;            // uniform: whole row can't contribute
  pa_scan<1>(L, sidx, sdist, boff, entries, s, threadIdx.x,
             nullptr, T, counters, cand, cap);
}

// ---------------- exact top-512: byte radix-select + bitonic sort ------------
__global__ __launch_bounds__(1024) void select_kernel(
    const uint64_t* __restrict__ cand, const unsigned int* __restrict__ counters,
    const int* __restrict__ sidx, const int* __restrict__ ridx,
    int* __restrict__ out, unsigned int cap) {
  __shared__ unsigned int h[256];
  __shared__ uint64_t topk[TOPK];
  __shared__ unsigned int cnt2;
  __shared__ uint64_t sh_prefix;
  __shared__ unsigned int sh_k;
  const int tid = threadIdx.x;
  unsigned int n = counters[0];
  if (n > cap) n = cap;
  if (tid == 0) { sh_prefix = 0; sh_k = TOPK; cnt2 = 0; }

  for (int byte = 7; byte >= 0; --byte) {
    for (int b = tid; b < 256; b += 1024) h[b] = 0;
    __syncthreads();
    const uint64_t prefix = sh_prefix;
    const uint64_t mask = (byte == 7) ? 0ull : (~0ull << (8 * (byte + 1)));
    for (unsigned int i = tid; i < n; i += 1024) {
      uint64_t key = cand[i];
      if ((key & mask) == prefix)
        atomicAdd(&h[(unsigned int)(key >> (8 * byte)) & 255u], 1u);
    }
    __syncthreads();
    if (tid == 0) {
      unsigned int k = sh_k, cum = 0; int chosen = 0;
      for (int v = 255; v >= 0; --v) {
        if (cum + h[v] >= k) { chosen = v; sh_k = k - cum; break; }
        cum += h[v];
      }
      sh_prefix = prefix | (((uint64_t)chosen) << (8 * byte));
    }
    __syncthreads();
  }
  const uint64_t kstar = sh_prefix;

  for (int t = tid; t < TOPK; t += 1024) topk[t] = 0;
  __syncthreads();
  for (unsigned int i = tid; i < n; i += 1024) {
    uint64_t key = cand[i];
    if (key >= kstar) {
      unsigned int pos = atomicAdd(&cnt2, 1u);
      if (pos < TOPK) topk[pos] = key;
    }
  }
  __syncthreads();

  for (int k2 = 2; k2 <= TOPK; k2 <<= 1) {
    for (int j2 = k2 >> 1; j2 > 0; j2 >>= 1) {
      if (tid < TOPK) {
        int ixj = tid ^ j2;
        if (ixj > tid) {
          bool asc = ((tid & k2) == 0);
          uint64_t a = topk[tid], b = topk[ixj];
          if (asc ? (a < b) : (a > b)) { topk[tid] = b; topk[ixj] = a; }
        }
      }
      __syncthreads();
    }
  }

  if (tid < TOPK) {
    uint64_t key = topk[tid];
    unsigned int idx = ~((unsigned int)key);
    if (idx >= 104857600u) idx = 0;           // safety clamp (degenerate only)
    unsigned int s   = idx / 51200u;          // n_r*K*K = 2048*25
    unsigned int rem = idx % 51200u;
    unsigned int r   = rem / 25u;
    unsigned int sij = rem % 25u;
    out[0 * TOPK + tid] = (int)s;                       // first_node_src
    out[1 * TOPK + tid] = (int)r;                       // first_node_ref
    out[2 * TOPK + tid] = sidx[s * NK + sij / 5u];      // second_node_src
    out[3 * TOPK + tid] = ridx[r * NK + sij % 5u];      // second_node_ref
  }
}

extern "C" void kernel_launch(void* const* d_in, const int* in_sizes, int n_in,
                              void* d_out, int out_size, void* d_ws, size_t ws_size,
                              hipStream_t stream) {
  const float* src = (const float*)d_in[0];
  const float* ref = (const float*)d_in[1];
  const float* L   = (const float*)d_in[2];
  char* ws = (char*)d_ws;
  int*                 sidx  = (int*)(ws + OFF_SIDX);
  float*               sdist = (float*)(ws + OFF_SDIST);
  int*                 ridx  = (int*)(ws + OFF_RIDX);
  float*               rdist = (float*)(ws + OFF_RDIST);
  unsigned int*        rmax  = (unsigned int*)(ws + OFF_RMAX);
  unsigned int*        cnts  = (unsigned int*)(ws + OFF_CNT);
  unsigned int*        bcnt  = (unsigned int*)(ws + OFF_BCNT);
  unsigned int*        bcur  = (unsigned int*)(ws + OFF_BCUR);
  unsigned int*        boff  = (unsigned int*)(ws + OFF_BOFF);
  unsigned long long*  ent   = (unsigned long long*)(ws + OFF_ENT);
  uint64_t*            cand  = (uint64_t*)(ws + OFF_CAND);
  int*                 out   = (int*)d_out;

  unsigned int cap = 0;
  if (ws_size > (size_t)OFF_CAND + 8) {
    size_t c = (ws_size - (size_t)OFF_CAND) / 8;
    cap = (c > CAP_MAX) ? CAP_MAX : (unsigned int)c;
  }

  hipMemsetAsync(ws + OFF_BCNT, 0, 512, stream);
  knn_kernel<<<512, 256, 0, stream>>>(src, ref, sidx, sdist, ridx, rdist);
  bcount_kernel<<<(NENT + 1023) / 1024, 1024, 0, stream>>>(rdist, bcnt);
  bprefix_kernel<<<1, 64, 0, stream>>>(bcnt, bcur, boff);
  bscatter_kernel<<<(NENT + 1023) / 1024, 1024, 0, stream>>>(rdist, ridx, bcur, ent);
  rowmax_kernel<<<N_PTS, 256, 0, stream>>>(L, sidx, sdist, boff, ent, rmax);
  thresh_kernel<<<1, 1024, 0, stream>>>(rmax, cnts);
  collect_kernel<<<N_PTS, 256, 0, stream>>>(L, sidx, sdist, boff, ent, rmax, cnts, cand, cap);
  select_kernel<<<1, 1024, 0, stream>>>(cand, cnts, sidx, ridx, out, cap);
}

// Round 13
// 329.897 us; speedup vs baseline: 1.5385x; 1.5385x over previous
//
#include <hip/hip_runtime.h>
#include <stdint.h>

#define N_PTS 2048
#define NK 5
#define TOPK 512
#define NBUCK 128
#define NENT (N_PTS * NK)        // 10240
#define CAP_MAX 262144u

// frozen arithmetic (r9-verified bit-exact vs np oracle):
//   d2 = fma(dz,dz, fma(dx,dx, dy*dy)); d = sqrt(max(d2,0))
//   q = fdiv(diff*diff, 0.01f); temp = max(1-q,0); v = (L*temp)*A
// tie rule: value desc, flat idx asc (key (vb<<32)|~idx descending)
// bound used for rejection (exact): temp<=1, A<1  =>  v <= fmul_rn(Lsr,temp) <= Lsr

// ws layout (bytes): same as r12
#define OFF_SIDX   0
#define OFF_SDIST  40960
#define OFF_RIDX   81920
#define OFF_RDIST  122880
#define OFF_RMAX   163840
#define OFF_CNT    172032
#define OFF_BCNT   172064
#define OFF_BCUR   172576
#define OFF_BOFF   173088
#define OFF_ENT    173616
#define OFF_CAND   255536

__device__ __forceinline__ unsigned long long shflxor64(unsigned long long v, int mask) {
  unsigned lo = (unsigned)v, hi = (unsigned)(v >> 32);
  lo = (unsigned)__shfl_xor((int)lo, mask);
  hi = (unsigned)__shfl_xor((int)hi, mask);
  return ((unsigned long long)hi << 32) | lo;
}

// ---------------- KNN: 512 blocks, 8 points/block, 32 lanes/point ------------
__global__ __launch_bounds__(256) void knn_kernel(
    const float* __restrict__ src, const float* __restrict__ ref,
    int* __restrict__ sidx, float* __restrict__ sdist,
    int* __restrict__ ridx, float* __restrict__ rdist) {
  __shared__ float sx[N_PTS], sy[N_PTS], sz[N_PTS];
  const bool is_ref = blockIdx.x >= 256;
  const float* pts = is_ref ? ref : src;
  int*   oidx  = is_ref ? ridx : sidx;
  float* odist = is_ref ? rdist : sdist;
  const int blk = is_ref ? (blockIdx.x - 256) : blockIdx.x;

  for (int t = threadIdx.x; t < N_PTS; t += 256) {
    sx[t] = pts[3 * t + 0];
    sy[t] = pts[3 * t + 1];
    sz[t] = pts[3 * t + 2];
  }
  __syncthreads();

  const int p = blk * 8 + (threadIdx.x >> 5);
  const int u = threadIdx.x & 31;
  const float px = sx[p], py = sy[p], pz = sz[p];

  unsigned long long best[6];
#pragma unroll
  for (int k = 0; k < 6; ++k) best[k] = ~0ull;

  for (int j = u; j < N_PTS; j += 32) {
    float dx = __fsub_rn(px, sx[j]);
    float dy = __fsub_rn(py, sy[j]);
    float dz = __fsub_rn(pz, sz[j]);
    float d2 = __builtin_fmaf(dz, dz,
                 __builtin_fmaf(dx, dx, __fmul_rn(dy, dy)));
    float d = __fsqrt_rn(fmaxf(d2, 0.0f));
    unsigned long long key = (((unsigned long long)__float_as_uint(d)) << 32)
                           | (unsigned)j;
    if (key < best[5]) {
      best[5] = key;
#pragma unroll
      for (int k = 5; k >= 1; --k)
        if (best[k] < best[k - 1]) {
          unsigned long long t = best[k]; best[k] = best[k - 1]; best[k - 1] = t;
        }
    }
  }

  int h = 0;
  unsigned long long win[6];
#pragma unroll
  for (int round = 0; round < 6; ++round) {
    unsigned long long my = (h < 6) ? best[h] : ~0ull;
    unsigned long long m = my;
#pragma unroll
    for (int msk = 16; msk >= 1; msk >>= 1) {
      unsigned long long o = shflxor64(m, msk);
      if (o < m) m = o;
    }
    win[round] = m;
    if (my == m) ++h;
  }

  if (u == 0) {
#pragma unroll
    for (int m = 1; m <= NK; ++m) {     // drop win[0] == self (d = 0)
      oidx[p * NK + m - 1]  = (int)(win[m] & 0xFFFFFFFFull);
      odist[p * NK + m - 1] = __uint_as_float((unsigned)(win[m] >> 32));
    }
  }
}

__device__ __forceinline__ int bucket_of(float rd) {
  int b = (int)(rd * 64.0f);
  if (b < 0) b = 0;
  if (b > NBUCK - 1) b = NBUCK - 1;
  return b;
}

// ---------------- bucket build: count / prefix / scatter ---------------------
__global__ __launch_bounds__(1024) void bcount_kernel(
    const float* __restrict__ rdist, unsigned int* __restrict__ bcnt) {
  int t = blockIdx.x * 1024 + threadIdx.x;
  if (t < NENT) atomicAdd(&bcnt[bucket_of(rdist[t])], 1u);
}

__global__ __launch_bounds__(64) void bprefix_kernel(
    const unsigned int* __restrict__ bcnt, unsigned int* __restrict__ bcur,
    unsigned int* __restrict__ boff) {
  if (threadIdx.x == 0) {
    unsigned int acc = 0;
    for (int b = 0; b < NBUCK; ++b) {
      boff[b] = acc;
      bcur[b] = acc;
      acc += bcnt[b];
    }
    boff[NBUCK] = acc;
  }
}

// entry: (rd_bits << 32) | (r << 14) | (j << 11) | rn
__global__ __launch_bounds__(1024) void bscatter_kernel(
    const float* __restrict__ rdist, const int* __restrict__ ridx,
    unsigned int* __restrict__ bcur, unsigned long long* __restrict__ entries) {
  int t = blockIdx.x * 1024 + threadIdx.x;
  if (t < NENT) {
    float rd = rdist[t];
    int r = t / NK, j = t % NK;
    unsigned int rn = (unsigned int)ridx[t];
    unsigned int pos = atomicAdd(&bcur[bucket_of(rd)], 1u);
    entries[pos] = (((unsigned long long)__float_as_uint(rd)) << 32)
                 | ((unsigned int)r << 14) | ((unsigned int)j << 11) | rn;
  }
}

// ---------------- pass 1: exact per-row max, A gathers only when needed ------
// Stage only Lrow in LDS (8 KB). Reject cells by upper bounds before touching
// A: v <= Lsr and v <= fmul_rn(Lsr,temp) (temp<=1, A<1, rounding-safe).
// Block-shared running max (LDS atomicMax over value bits) makes the gather
// count per row collapse to ~warm-up + a handful. smax only ever set from
// exactly-computed v => rowmax exact => T identical => output bit-identical.
__global__ __launch_bounds__(256) void rowmax_kernel(
    const float* __restrict__ L,
    const int* __restrict__ sidx, const float* __restrict__ sdist,
    const unsigned int* __restrict__ boff,
    const unsigned long long* __restrict__ entries,
    unsigned int* __restrict__ rowmax) {
  __shared__ float Lrow[N_PTS];
  __shared__ float sdsh[NK];
  __shared__ int   snsh[NK];
  __shared__ unsigned int s_max;
  const int s = blockIdx.x, tid = threadIdx.x;
  if (tid < NK) { snsh[tid] = sidx[s * NK + tid]; sdsh[tid] = sdist[s * NK + tid]; }
  if (tid == 0) s_max = 0;
  // coalesced float4 staging of this block's L row
  {
    const float4* src4 = (const float4*)(L + (size_t)s * N_PTS);
    float4* dst4 = (float4*)Lrow;
    for (int c = tid; c < N_PTS / 4; c += 256) dst4[c] = src4[c];
  }
  __syncthreads();

  volatile unsigned int* vmax = &s_max;

#pragma unroll
  for (int i = 0; i < NK; ++i) {
    const float sd_i = sdsh[i];
    const float* __restrict__ Arow = L + (size_t)snsh[i] * N_PTS;
    float lo = __fsub_rn(sd_i, 0.1005f);
    float hi = __fadd_rn(sd_i, 0.1005f);
    unsigned int e0 = boff[bucket_of(lo)], e1 = boff[bucket_of(hi) + 1];
    for (unsigned int e = e0 + tid; e < e1; e += 256) {
      unsigned long long ent = entries[e];
      float rdv = __uint_as_float((unsigned int)(ent >> 32));
      float diff = __fsub_rn(sd_i, rdv);
      float dsq  = __fmul_rn(diff, diff);
      if (dsq >= 0.0101f) continue;                      // temp provably 0
      unsigned int lo32 = (unsigned int)ent;
      unsigned int r  = (lo32 >> 14) & 0x7FFu;
      float Lsr = Lrow[r];
      float smax_f = __uint_as_float(*vmax);
      if (Lsr <= smax_f) continue;                       // v <= Lsr
      float q    = __fdiv_rn(dsq, 0.01f);
      float temp = fmaxf(__fsub_rn(1.0f, q), 0.0f);
      float ub   = __fmul_rn(Lsr, temp);                 // frozen inner term
      if (ub <= smax_f) continue;                        // v <= ub
      unsigned int rn = lo32 & 0x7FFu;
      float v = __fmul_rn(ub, Arow[rn]);                 // frozen chain
      unsigned int vb = __float_as_uint(v);
      if (v > 0.0f && vb > *vmax) atomicMax(&s_max, vb);
    }
  }
  __syncthreads();
  if (tid == 0) rowmax[s] = s_max;
}

// ---------------- threshold: T = 512th-largest row max; zero counter ---------
__global__ __launch_bounds__(1024) void thresh_kernel(
    const unsigned int* __restrict__ rowmax, unsigned int* __restrict__ counters) {
  __shared__ unsigned int a[N_PTS];
  const int tid = threadIdx.x;
  for (int t = tid; t < N_PTS; t += 1024) a[t] = rowmax[t];
  __syncthreads();
  for (int k2 = 2; k2 <= N_PTS; k2 <<= 1) {
    for (int j2 = k2 >> 1; j2 > 0; j2 >>= 1) {
      for (int e = 0; e < N_PTS / 1024; ++e) {
        int i = tid + e * 1024;
        int pj = i ^ j2;
        if (pj > i) {
          bool blk = ((i & k2) == 0);
          unsigned int x = a[i], y = a[pj];
          if (blk ? (x < y) : (x > y)) { a[i] = y; a[pj] = x; }
        }
      }
      __syncthreads();
    }
  }
  if (tid == 0) {
    counters[3] = a[TOPK - 1];
    counters[0] = 0;
  }
}

// ---------------- pass 2: collect, static rejection vs T ---------------------
__global__ __launch_bounds__(256) void collect_kernel(
    const float* __restrict__ L,
    const int* __restrict__ sidx, const float* __restrict__ sdist,
    const unsigned int* __restrict__ boff,
    const unsigned long long* __restrict__ entries,
    const unsigned int* __restrict__ rowmax,
    unsigned int* __restrict__ counters, uint64_t* __restrict__ cand,
    unsigned int cap) {
  __shared__ float Lrow[N_PTS];
  __shared__ float sdsh[NK];
  __shared__ int   snsh[NK];
  const int s = blockIdx.x, tid = threadIdx.x;
  const unsigned int T = counters[3];
  if (rowmax[s] < T) return;            // uniform: whole row can't contribute
  const float T_f = __uint_as_float(T);
  if (tid < NK) { snsh[tid] = sidx[s * NK + tid]; sdsh[tid] = sdist[s * NK + tid]; }
  {
    const float4* src4 = (const float4*)(L + (size_t)s * N_PTS);
    float4* dst4 = (float4*)Lrow;
    for (int c = tid; c < N_PTS / 4; c += 256) dst4[c] = src4[c];
  }
  __syncthreads();

#pragma unroll
  for (int i = 0; i < NK; ++i) {
    const float sd_i = sdsh[i];
    const float* __restrict__ Arow = L + (size_t)snsh[i] * N_PTS;
    float lo = __fsub_rn(sd_i, 0.1005f);
    float hi = __fadd_rn(sd_i, 0.1005f);
    unsigned int e0 = boff[bucket_of(lo)], e1 = boff[bucket_of(hi) + 1];
    for (unsigned int e = e0 + tid; e < e1; e += 256) {
      unsigned long long ent = entries[e];
      float rdv = __uint_as_float((unsigned int)(ent >> 32));
      float diff = __fsub_rn(sd_i, rdv);
      float dsq  = __fmul_rn(diff, diff);
      if (dsq >= 0.0101f) continue;
      unsigned int lo32 = (unsigned int)ent;
      unsigned int r  = (lo32 >> 14) & 0x7FFu;
      float Lsr = Lrow[r];
      if (Lsr < T_f) continue;                           // v <= Lsr < T
      float q    = __fdiv_rn(dsq, 0.01f);
      float temp = fmaxf(__fsub_rn(1.0f, q), 0.0f);
      float ub   = __fmul_rn(Lsr, temp);
      if (ub < T_f) continue;                            // v <= ub < T
      unsigned int rn = lo32 & 0x7FFu;
      float v = __fmul_rn(ub, Arow[rn]);                 // frozen chain
      unsigned int vb = __float_as_uint(v);
      if (v > 0.0f && vb >= T) {
        unsigned int j = (lo32 >> 11) & 7u;
        unsigned int pos = atomicAdd(&counters[0], 1u);
        if (pos < cap) {
          unsigned int idx = ((unsigned int)s * (unsigned int)N_PTS + r) * 25u
                           + (unsigned int)i * 5u + j;
          cand[pos] = (((uint64_t)vb) << 32) | (uint64_t)((uint32_t)(~idx));
        }
      }
    }
  }
}

// ---------------- exact top-512: byte radix-select + bitonic sort ------------
__global__ __launch_bounds__(1024) void select_kernel(
    const uint64_t* __restrict__ cand, const unsigned int* __restrict__ counters,
    const int* __restrict__ sidx, const int* __restrict__ ridx,
    int* __restrict__ out, unsigned int cap) {
  __shared__ unsigned int h[256];
  __shared__ uint64_t topk[TOPK];
  __shared__ unsigned int cnt2;
  __shared__ uint64_t sh_prefix;
  __shared__ unsigned int sh_k;
  const int tid = threadIdx.x;
  unsigned int n = counters[0];
  if (n > cap) n = cap;
  if (tid == 0) { sh_prefix = 0; sh_k = TOPK; cnt2 = 0; }

  for (int byte = 7; byte >= 0; --byte) {
    for (int b = tid; b < 256; b += 1024) h[b] = 0;
    __syncthreads();
    const uint64_t prefix = sh_prefix;
    const uint64_t mask = (byte == 7) ? 0ull : (~0ull << (8 * (byte + 1)));
    for (unsigned int i = tid; i < n; i += 1024) {
      uint64_t key = cand[i];
      if ((key & mask) == prefix)
        atomicAdd(&h[(unsigned int)(key >> (8 * byte)) & 255u], 1u);
    }
    __syncthreads();
    if (tid == 0) {
      unsigned int k = sh_k, cum = 0; int chosen = 0;
      for (int v = 255; v >= 0; --v) {
        if (cum + h[v] >= k) { chosen = v; sh_k = k - cum; break; }
        cum += h[v];
      }
      sh_prefix = prefix | (((uint64_t)chosen) << (8 * byte));
    }
    __syncthreads();
  }
  const uint64_t kstar = sh_prefix;

  for (int t = tid; t < TOPK; t += 1024) topk[t] = 0;
  __syncthreads();
  for (unsigned int i = tid; i < n; i += 1024) {
    uint64_t key = cand[i];
    if (key >= kstar) {
      unsigned int pos = atomicAdd(&cnt2, 1u);
      if (pos < TOPK) topk[pos] = key;
    }
  }
  __syncthreads();

  for (int k2 = 2; k2 <= TOPK; k2 <<= 1) {
    for (int j2 = k2 >> 1; j2 > 0; j2 >>= 1) {
      if (tid < TOPK) {
        int ixj = tid ^ j2;
        if (ixj > tid) {
          bool asc = ((tid & k2) == 0);
          uint64_t a = topk[tid], b = topk[ixj];
          if (asc ? (a < b) : (a > b)) { topk[tid] = b; topk[ixj] = a; }
        }
      }
      __syncthreads();
    }
  }

  if (tid < TOPK) {
    uint64_t key = topk[tid];
    unsigned int idx = ~((unsigned int)key);
    if (idx >= 104857600u) idx = 0;           // safety clamp (degenerate only)
    unsigned int s   = idx / 51200u;          // n_r*K*K = 2048*25
    unsigned int rem = idx % 51200u;
    unsigned int r   = rem / 25u;
    unsigned int sij = rem % 25u;
    out[0 * TOPK + tid] = (int)s;                       // first_node_src
    out[1 * TOPK + tid] = (int)r;                       // first_node_ref
    out[2 * TOPK + tid] = sidx[s * NK + sij / 5u];      // second_node_src
    out[3 * TOPK + tid] = ridx[r * NK + sij % 5u];      // second_node_ref
  }
}

extern "C" void kernel_launch(void* const* d_in, const int* in_sizes, int n_in,
                              void* d_out, int out_size, void* d_ws, size_t ws_size,
                              hipStream_t stream) {
  const float* src = (const float*)d_in[0];
  const float* ref = (const float*)d_in[1];
  const float* L   = (const float*)d_in[2];
  char* ws = (char*)d_ws;
  int*                 sidx  = (int*)(ws + OFF_SIDX);
  float*               sdist = (float*)(ws + OFF_SDIST);
  int*                 ridx  = (int*)(ws + OFF_RIDX);
  float*               rdist = (float*)(ws + OFF_RDIST);
  unsigned int*        rmax  = (unsigned int*)(ws + OFF_RMAX);
  unsigned int*        cnts  = (unsigned int*)(ws + OFF_CNT);
  unsigned int*        bcnt  = (unsigned int*)(ws + OFF_BCNT);
  unsigned int*        bcur  = (unsigned int*)(ws + OFF_BCUR);
  unsigned int*        boff  = (unsigned int*)(ws + OFF_BOFF);
  unsigned long long*  ent   = (unsigned long long*)(ws + OFF_ENT);
  uint64_t*            cand  = (uint64_t*)(ws + OFF_CAND);
  int*                 out   = (int*)d_out;

  unsigned int cap = 0;
  if (ws_size > (size_t)OFF_CAND + 8) {
    size_t c = (ws_size - (size_t)OFF_CAND) / 8;
    cap = (c > CAP_MAX) ? CAP_MAX : (unsigned int)c;
  }

  hipMemsetAsync(ws + OFF_BCNT, 0, 512, stream);
  knn_kernel<<<512, 256, 0, stream>>>(src, ref, sidx, sdist, ridx, rdist);
  bcount_kernel<<<(NENT + 1023) / 1024, 1024, 0, stream>>>(rdist, bcnt);
  bprefix_kernel<<<1, 64, 0, stream>>>(bcnt, bcur, boff);
  bscatter_kernel<<<(NENT + 1023) / 1024, 1024, 0, stream>>>(rdist, ridx, bcur, ent);
  rowmax_kernel<<<N_PTS, 256, 0, stream>>>(L, sidx, sdist, boff, ent, rmax);
  thresh_kernel<<<1, 1024, 0, stream>>>(rmax, cnts);
  collect_kernel<<<N_PTS, 256, 0, stream>>>(L, sidx, sdist, boff, ent, rmax, cnts, cand, cap);
  select_kernel<<<1, 1024, 0, stream>>>(cand, cnts, sidx, ridx, out, cap);
}

// Round 14
// 274.689 us; speedup vs baseline: 1.8477x; 1.2010x over previous
//
#include <hip/hip_runtime.h>
#include <stdint.h>

#define N_PTS 2048
#define NK 5
#define TOPK 512
#define CAP_MAX 262144u

// frozen arithmetic (r9-verified bit-exact vs np oracle):
//   d2 = fma(dz,dz, fma(dx,dx, dy*dy)); d = sqrt(max(d2,0))
//   q = fdiv(diff*diff, 0.01f); temp = max(1-q,0); v = (L*temp)*A
// tie rule: value desc, flat idx asc (key (vb<<32)|~idx descending)
// rejection bounds (exact under rounding, temp<=1, A<1):
//   v <= fmul_rn(Lsr,temp) <= Lsr

// ws layout (bytes):
//      0  src_ne_idx   int[10240]    (40960)
//  40960  src_ne_dist  f32[10240]    (40960)
//  81920  ref_ne_idx   int[10240]    (40960)
// 122880  ref_ne_dist  f32[10240]    (40960)
// 163840  rowmax       uint[2048]    (8192)
// 172032  counters     uint[8]       (32)   [0]=cand_count [3]=T
// 172064  cand         uint64[cap]
#define OFF_SIDX   0
#define OFF_SDIST  40960
#define OFF_RIDX   81920
#define OFF_RDIST  122880
#define OFF_RMAX   163840
#define OFF_CNT    172032
#define OFF_CAND   172064

__device__ __forceinline__ unsigned long long shflxor64(unsigned long long v, int mask) {
  unsigned lo = (unsigned)v, hi = (unsigned)(v >> 32);
  lo = (unsigned)__shfl_xor((int)lo, mask);
  hi = (unsigned)__shfl_xor((int)hi, mask);
  return ((unsigned long long)hi << 32) | lo;
}

// ---------------- KNN: 512 blocks, 8 points/block, 32 lanes/point ------------
__global__ __launch_bounds__(256) void knn_kernel(
    const float* __restrict__ src, const float* __restrict__ ref,
    int* __restrict__ sidx, float* __restrict__ sdist,
    int* __restrict__ ridx, float* __restrict__ rdist) {
  __shared__ float sx[N_PTS], sy[N_PTS], sz[N_PTS];
  const bool is_ref = blockIdx.x >= 256;
  const float* pts = is_ref ? ref : src;
  int*   oidx  = is_ref ? ridx : sidx;
  float* odist = is_ref ? rdist : sdist;
  const int blk = is_ref ? (blockIdx.x - 256) : blockIdx.x;

  for (int t = threadIdx.x; t < N_PTS; t += 256) {
    sx[t] = pts[3 * t + 0];
    sy[t] = pts[3 * t + 1];
    sz[t] = pts[3 * t + 2];
  }
  __syncthreads();

  const int p = blk * 8 + (threadIdx.x >> 5);
  const int u = threadIdx.x & 31;
  const float px = sx[p], py = sy[p], pz = sz[p];

  unsigned long long best[6];
#pragma unroll
  for (int k = 0; k < 6; ++k) best[k] = ~0ull;

  for (int j = u; j < N_PTS; j += 32) {
    float dx = __fsub_rn(px, sx[j]);
    float dy = __fsub_rn(py, sy[j]);
    float dz = __fsub_rn(pz, sz[j]);
    float d2 = __builtin_fmaf(dz, dz,
                 __builtin_fmaf(dx, dx, __fmul_rn(dy, dy)));
    float d = __fsqrt_rn(fmaxf(d2, 0.0f));
    unsigned long long key = (((unsigned long long)__float_as_uint(d)) << 32)
                           | (unsigned)j;
    if (key < best[5]) {
      best[5] = key;
#pragma unroll
      for (int k = 5; k >= 1; --k)
        if (best[k] < best[k - 1]) {
          unsigned long long t = best[k]; best[k] = best[k - 1]; best[k - 1] = t;
        }
    }
  }

  int h = 0;
  unsigned long long win[6];
#pragma unroll
  for (int round = 0; round < 6; ++round) {
    unsigned long long my = (h < 6) ? best[h] : ~0ull;
    unsigned long long m = my;
#pragma unroll
    for (int msk = 16; msk >= 1; msk >>= 1) {
      unsigned long long o = shflxor64(m, msk);
      if (o < m) m = o;
    }
    win[round] = m;
    if (my == m) ++h;
  }

  if (u == 0) {
#pragma unroll
    for (int m = 1; m <= NK; ++m) {     // drop win[0] == self (d = 0)
      oidx[p * NK + m - 1]  = (int)(win[m] & 0xFFFFFFFFull);
      odist[p * NK + m - 1] = __uint_as_float((unsigned)(win[m] >> 32));
    }
  }
}

// ---------------- pass 1: exact per-row max via Lsr-first rejection ----------
// Iterate r directly; Lsr (upper bound on every v in column r) <= running max
// rejects ~all r after warm-up. Survivors compute their 25 cells with the
// frozen chain; A gathers only when ub beats the running max. smax only ever
// holds exactly-computed v => rowmax exact => T identical => output identical.
__global__ __launch_bounds__(256) void rowmax_kernel(
    const float* __restrict__ L,
    const int* __restrict__ sidx, const float* __restrict__ sdist,
    const int* __restrict__ ridx, const float* __restrict__ rdist,
    unsigned int* __restrict__ rowmax) {
  __shared__ float Lrow[N_PTS];
  __shared__ float sdsh[NK];
  __shared__ int   snsh[NK];
  __shared__ unsigned int s_max;
  const int s = blockIdx.x, tid = threadIdx.x;
  if (tid < NK) { snsh[tid] = sidx[s * NK + tid]; sdsh[tid] = sdist[s * NK + tid]; }
  if (tid == 0) s_max = 0;
  {
    const float4* src4 = (const float4*)(L + (size_t)s * N_PTS);
    float4* dst4 = (float4*)Lrow;
    for (int c = tid; c < N_PTS / 4; c += 256) dst4[c] = src4[c];
  }
  __syncthreads();

  float sd[NK];
#pragma unroll
  for (int i = 0; i < NK; ++i) sd[i] = sdsh[i];
  volatile unsigned int* vmax = &s_max;

  for (int r = tid; r < N_PTS; r += 256) {
    float Lsr = Lrow[r];
    if (Lsr <= __uint_as_float(*vmax)) continue;         // v <= Lsr <= smax
    float rd[NK]; int rn[NK];
#pragma unroll
    for (int j = 0; j < NK; ++j) { rd[j] = rdist[r * NK + j]; rn[j] = ridx[r * NK + j]; }
    unsigned int lmax = *vmax;
#pragma unroll
    for (int i = 0; i < NK; ++i) {
      const float* __restrict__ Arow = L + (size_t)snsh[i] * N_PTS;
#pragma unroll
      for (int j = 0; j < NK; ++j) {
        float diff = __fsub_rn(sd[i], rd[j]);
        float dsq  = __fmul_rn(diff, diff);
        if (dsq >= 0.0101f) continue;                    // temp provably 0
        float q    = __fdiv_rn(dsq, 0.01f);
        float temp = fmaxf(__fsub_rn(1.0f, q), 0.0f);
        if (temp <= 0.0f) continue;
        float ub   = __fmul_rn(Lsr, temp);               // frozen inner term
        if (__float_as_uint(ub) <= lmax && ub <= __uint_as_float(*vmax)) continue;
        float v = __fmul_rn(ub, Arow[rn[j]]);            // frozen chain
        unsigned int vb = __float_as_uint(v);
        if (v > 0.0f && vb > lmax) lmax = vb;
      }
    }
    if (lmax > *vmax) atomicMax(&s_max, lmax);
  }
  __syncthreads();
  if (tid == 0) rowmax[s] = s_max;
}

// ---------------- threshold: T = 512th-largest row max; zero counter ---------
// count(v >= T) >= 512 guaranteed: each of the top-512 rows contributes >= 1.
__global__ __launch_bounds__(1024) void thresh_kernel(
    const unsigned int* __restrict__ rowmax, unsigned int* __restrict__ counters) {
  __shared__ unsigned int a[N_PTS];
  const int tid = threadIdx.x;
  for (int t = tid; t < N_PTS; t += 1024) a[t] = rowmax[t];
  __syncthreads();
  for (int k2 = 2; k2 <= N_PTS; k2 <<= 1) {
    for (int j2 = k2 >> 1; j2 > 0; j2 >>= 1) {
      for (int e = 0; e < N_PTS / 1024; ++e) {
        int i = tid + e * 1024;
        int pj = i ^ j2;
        if (pj > i) {
          bool blk = ((i & k2) == 0);
          unsigned int x = a[i], y = a[pj];
          if (blk ? (x < y) : (x > y)) { a[i] = y; a[pj] = x; }
        }
      }
      __syncthreads();
    }
  }
  if (tid == 0) {
    counters[3] = a[TOPK - 1];
    counters[0] = 0;
  }
}

// ---------------- pass 2: collect, static Lsr < T rejection ------------------
__global__ __launch_bounds__(256) void collect_kernel(
    const float* __restrict__ L,
    const int* __restrict__ sidx, const float* __restrict__ sdist,
    const int* __restrict__ ridx, const float* __restrict__ rdist,
    const unsigned int* __restrict__ rowmax,
    unsigned int* __restrict__ counters, uint64_t* __restrict__ cand,
    unsigned int cap) {
  __shared__ float Lrow[N_PTS];
  __shared__ float sdsh[NK];
  __shared__ int   snsh[NK];
  const int s = blockIdx.x, tid = threadIdx.x;
  const unsigned int T = counters[3];
  if (rowmax[s] < T) return;            // uniform: whole row can't contribute
  const float T_f = __uint_as_float(T);
  if (tid < NK) { snsh[tid] = sidx[s * NK + tid]; sdsh[tid] = sdist[s * NK + tid]; }
  {
    const float4* src4 = (const float4*)(L + (size_t)s * N_PTS);
    float4* dst4 = (float4*)Lrow;
    for (int c = tid; c < N_PTS / 4; c += 256) dst4[c] = src4[c];
  }
  __syncthreads();

  float sd[NK];
#pragma unroll
  for (int i = 0; i < NK; ++i) sd[i] = sdsh[i];

  for (int r = tid; r < N_PTS; r += 256) {
    float Lsr = Lrow[r];
    if (Lsr < T_f) continue;                             // v <= Lsr < T
    float rd[NK]; int rn[NK];
#pragma unroll
    for (int j = 0; j < NK; ++j) { rd[j] = rdist[r * NK + j]; rn[j] = ridx[r * NK + j]; }
#pragma unroll
    for (int i = 0; i < NK; ++i) {
      const float* __restrict__ Arow = L + (size_t)snsh[i] * N_PTS;
#pragma unroll
      for (int j = 0; j < NK; ++j) {
        float diff = __fsub_rn(sd[i], rd[j]);
        float dsq  = __fmul_rn(diff, diff);
        if (dsq >= 0.0101f) continue;
        float q    = __fdiv_rn(dsq, 0.01f);
        float temp = fmaxf(__fsub_rn(1.0f, q), 0.0f);
        if (temp <= 0.0f) continue;
        float ub   = __fmul_rn(Lsr, temp);
        if (ub < T_f) continue;                          // v <= ub < T
        float v = __fmul_rn(ub, Arow[rn[j]]);            // frozen chain
        unsigned int vb = __float_as_uint(v);
        if (v > 0.0f && vb >= T) {
          unsigned int pos = atomicAdd(&counters[0], 1u);
          if (pos < cap) {
            unsigned int idx = ((unsigned int)s * (unsigned int)N_PTS
                                + (unsigned int)r) * 25u
                             + (unsigned int)i * 5u + (unsigned int)j;
            cand[pos] = (((uint64_t)vb) << 32) | (uint64_t)((uint32_t)(~idx));
          }
        }
      }
    }
  }
}

// ---------------- exact top-512: byte radix-select + bitonic sort ------------
__global__ __launch_bounds__(1024) void select_kernel(
    const uint64_t* __restrict__ cand, const unsigned int* __restrict__ counters,
    const int* __restrict__ sidx, const int* __restrict__ ridx,
    int* __restrict__ out, unsigned int cap) {
  __shared__ unsigned int h[256];
  __shared__ uint64_t topk[TOPK];
  __shared__ unsigned int cnt2;
  __shared__ uint64_t sh_prefix;
  __shared__ unsigned int sh_k;
  const int tid = threadIdx.x;
  unsigned int n = counters[0];
  if (n > cap) n = cap;
  if (tid == 0) { sh_prefix = 0; sh_k = TOPK; cnt2 = 0; }

  for (int byte = 7; byte >= 0; --byte) {
    for (int b = tid; b < 256; b += 1024) h[b] = 0;
    __syncthreads();
    const uint64_t prefix = sh_prefix;
    const uint64_t mask = (byte == 7) ? 0ull : (~0ull << (8 * (byte + 1)));
    for (unsigned int i = tid; i < n; i += 1024) {
      uint64_t key = cand[i];
      if ((key & mask) == prefix)
        atomicAdd(&h[(unsigned int)(key >> (8 * byte)) & 255u], 1u);
    }
    __syncthreads();
    if (tid == 0) {
      unsigned int k = sh_k, cum = 0; int chosen = 0;
      for (int v = 255; v >= 0; --v) {
        if (cum + h[v] >= k) { chosen = v; sh_k = k - cum; break; }
        cum += h[v];
      }
      sh_prefix = prefix | (((uint64_t)chosen) << (8 * byte));
    }
    __syncthreads();
  }
  const uint64_t kstar = sh_prefix;

  for (int t = tid; t < TOPK; t += 1024) topk[t] = 0;
  __syncthreads();
  for (unsigned int i = tid; i < n; i += 1024) {
    uint64_t key = cand[i];
    if (key >= kstar) {
      unsigned int pos = atomicAdd(&cnt2, 1u);
      if (pos < TOPK) topk[pos] = key;
    }
  }
  __syncthreads();

  for (int k2 = 2; k2 <= TOPK; k2 <<= 1) {
    for (int j2 = k2 >> 1; j2 > 0; j2 >>= 1) {
      if (tid < TOPK) {
        int ixj = tid ^ j2;
        if (ixj > tid) {
          bool asc = ((tid & k2) == 0);
          uint64_t a = topk[tid], b = topk[ixj];
          if (asc ? (a < b) : (a > b)) { topk[tid] = b; topk[ixj] = a; }
        }
      }
      __syncthreads();
    }
  }

  if (tid < TOPK) {
    uint64_t key = topk[tid];
    unsigned int idx = ~((unsigned int)key);
    if (idx >= 104857600u) idx = 0;           // safety clamp (degenerate only)
    unsigned int s   = idx / 51200u;          // n_r*K*K = 2048*25
    unsigned int rem = idx % 51200u;
    unsigned int r   = rem / 25u;
    unsigned int sij = rem % 25u;
    out[0 * TOPK + tid] = (int)s;                       // first_node_src
    out[1 * TOPK + tid] = (int)r;                       // first_node_ref
    out[2 * TOPK + tid] = sidx[s * NK + sij / 5u];      // second_node_src
    out[3 * TOPK + tid] = ridx[r * NK + sij % 5u];      // second_node_ref
  }
}

extern "C" void kernel_launch(void* const* d_in, const int* in_sizes, int n_in,
                              void* d_out, int out_size, void* d_ws, size_t ws_size,
                              hipStream_t stream) {
  const float* src = (const float*)d_in[0];
  const float* ref = (const float*)d_in[1];
  const float* L   = (const float*)d_in[2];
  char* ws = (char*)d_ws;
  int*          sidx  = (int*)(ws + OFF_SIDX);
  float*        sdist = (float*)(ws + OFF_SDIST);
  int*          ridx  = (int*)(ws + OFF_RIDX);
  float*        rdist = (float*)(ws + OFF_RDIST);
  unsigned int* rmax  = (unsigned int*)(ws + OFF_RMAX);
  unsigned int* cnts  = (unsigned int*)(ws + OFF_CNT);
  uint64_t*     cand  = (uint64_t*)(ws + OFF_CAND);
  int*          out   = (int*)d_out;

  unsigned int cap = 0;
  if (ws_size > (size_t)OFF_CAND + 8) {
    size_t c = (ws_size - (size_t)OFF_CAND) / 8;
    cap = (c > CAP_MAX) ? CAP_MAX : (unsigned int)c;
  }

  knn_kernel<<<512, 256, 0, stream>>>(src, ref, sidx, sdist, ridx, rdist);
  rowmax_kernel<<<N_PTS, 256, 0, stream>>>(L, sidx, sdist, ridx, rdist, rmax);
  thresh_kernel<<<1, 1024, 0, stream>>>(rmax, cnts);
  collect_kernel<<<N_PTS, 256, 0, stream>>>(L, sidx, sdist, ridx, rdist, rmax, cnts, cand, cap);
  select_kernel<<<1, 1024, 0, stream>>>(cand, cnts, sidx, ridx, out, cap);
}